// Round 7
// baseline (380.026 us; speedup 1.0000x reference)
//
#include <hip/hip_runtime.h>
#include <hip/hip_bf16.h>

#define NN 50000
#define NE 800000
#define BN_EPS 1e-5f
#define CHUNK 8192
#define NCH 98     // ceil(NE / CHUNK)
#define NBK 196    // ceil(NN / 256) dst-buckets

typedef __attribute__((ext_vector_type(4))) float f32x4;

// ---------------- utility: zero ints (bcnt + sums) ----------------
__global__ void zero_k(int* __restrict__ p, int n) {
    int i = blockIdx.x * 256 + threadIdx.x;
    if (i < n) p[i] = 0;
}

// ---------------- bucket histogram: bucket = dst >> 8 ----------------
__global__ void bhist_k(const int* __restrict__ dst, int* __restrict__ bcnt) {
    __shared__ int c[256];
    int t = threadIdx.x;
    c[t] = 0;
    __syncthreads();
    int base = blockIdx.x * CHUNK;
    int n = NE - base; if (n > CHUNK) n = CHUNK;
    for (int i = t; i < n; i += 256) atomicAdd(&c[dst[base + i] >> 8], 1);
    __syncthreads();
    if (c[t]) atomicAdd(&bcnt[t], c[t]);
}

// ---------------- scan bucket counts -> bbase/bres ----------------
__global__ void bscan_k(const int* __restrict__ bcnt, int* __restrict__ bbase,
                        int* __restrict__ bres, int* __restrict__ off) {
    __shared__ int s[256];
    int t = threadIdx.x;
    int v = bcnt[t];
    s[t] = v;
    __syncthreads();
    for (int d = 1; d < 256; d <<= 1) {
        int u = (t >= d) ? s[t - d] : 0;
        __syncthreads();
        s[t] += u;
        __syncthreads();
    }
    int ex = s[t] - v;
    bbase[t] = ex;
    bres[t] = ex;
    if (t == 0) { bbase[256] = NE; off[NN] = NE; }
}

// ---------------- bucket scatter: chunk -> bucket-ordered global ebuf ---------
// packed int: src (16b) | dst&255 (8b) | bucket (8b)
__global__ void bscatter_k(const int* __restrict__ src, const int* __restrict__ dst,
                           int* __restrict__ bres, int* __restrict__ ebuf) {
    __shared__ int cnt[256], loff[256], lcur[256], gst[256], sc[256];
    __shared__ int packed[CHUNK];
    int t = threadIdx.x;
    cnt[t] = 0;
    __syncthreads();
    int base = blockIdx.x * CHUNK;
    int n = NE - base; if (n > CHUNK) n = CHUNK;
    for (int i = t; i < n; i += 256) atomicAdd(&cnt[dst[base + i] >> 8], 1);
    __syncthreads();
    sc[t] = cnt[t];
    __syncthreads();
    for (int d = 1; d < 256; d <<= 1) {
        int u = (t >= d) ? sc[t - d] : 0;
        __syncthreads();
        sc[t] += u;
        __syncthreads();
    }
    loff[t] = sc[t] - cnt[t];
    lcur[t] = loff[t];
    __syncthreads();
    for (int i = t; i < n; i += 256) {
        int d = dst[base + i];
        int b = d >> 8;
        int p = atomicAdd(&lcur[b], 1);
        packed[p] = src[base + i] | ((d & 255) << 16) | (b << 24);
    }
    __syncthreads();
    if (cnt[t]) gst[t] = atomicAdd(&bres[t], cnt[t]);
    __syncthreads();
    for (int i = t; i < n; i += 256) {
        int v = packed[i];
        int b = (v >> 24) & 255;
        ebuf[gst[b] + i - loff[b]] = v & 0xFFFFFF;
    }
}

// ---------------- per-bucket CSR: off[] + adj[] (all writes XCD-local) --------
__global__ void csr_k(const int* __restrict__ bbase, const int* __restrict__ ebuf,
                      int* __restrict__ off, int* __restrict__ adj) {
    __shared__ int cnt[256], loff[256], lcur[256], sc[256];
    int b = blockIdx.x, t = threadIdx.x;
    int s0 = bbase[b], s1 = bbase[b + 1];
    int n = s1 - s0;
    cnt[t] = 0;
    __syncthreads();
    for (int i = t; i < n; i += 256) atomicAdd(&cnt[(ebuf[s0 + i] >> 16) & 255], 1);
    __syncthreads();
    sc[t] = cnt[t];
    __syncthreads();
    for (int d = 1; d < 256; d <<= 1) {
        int u = (t >= d) ? sc[t - d] : 0;
        __syncthreads();
        sc[t] += u;
        __syncthreads();
    }
    loff[t] = sc[t] - cnt[t];
    lcur[t] = loff[t];
    int node = b * 256 + t;
    if (node < NN) off[node] = s0 + loff[t];
    __syncthreads();
    for (int i = t; i < n; i += 256) {
        int v = ebuf[s0 + i];
        int p = atomicAdd(&lcur[(v >> 16) & 255], 1);
        adj[s0 + p] = v & 0xFFFF;
    }
}

// ---------------- gather one node's aggregated feature (lane = feature) -------
__device__ __forceinline__ float gather_row(const float* __restrict__ X, int ldx,
                                            int lane, const int* __restrict__ off,
                                            const int* __restrict__ adj, int node) {
    float acc = X[(size_t)node * ldx + lane];
    int s = off[node], e = off[node + 1];
    int p = s;
    for (; p + 8 <= e; p += 8) {
        int j0 = adj[p + 0], j1 = adj[p + 1], j2 = adj[p + 2], j3 = adj[p + 3];
        int j4 = adj[p + 4], j5 = adj[p + 5], j6 = adj[p + 6], j7 = adj[p + 7];
        float v0 = X[(size_t)j0 * ldx + lane];
        float v1 = X[(size_t)j1 * ldx + lane];
        float v2 = X[(size_t)j2 * ldx + lane];
        float v3 = X[(size_t)j3 * ldx + lane];
        float v4 = X[(size_t)j4 * ldx + lane];
        float v5 = X[(size_t)j5 * ldx + lane];
        float v6 = X[(size_t)j6 * ldx + lane];
        float v7 = X[(size_t)j7 * ldx + lane];
        acc += ((v0 + v1) + (v2 + v3)) + ((v4 + v5) + (v6 + v7));
    }
    if (p + 4 <= e) {
        int j0 = adj[p + 0], j1 = adj[p + 1], j2 = adj[p + 2], j3 = adj[p + 3];
        float v0 = X[(size_t)j0 * ldx + lane];
        float v1 = X[(size_t)j1 * ldx + lane];
        float v2 = X[(size_t)j2 * ldx + lane];
        float v3 = X[(size_t)j3 * ldx + lane];
        acc += (v0 + v1) + (v2 + v3);
        p += 4;
    }
    for (; p < e; p++) acc += X[(size_t)adj[p] * ldx + lane];
    return acc;
}

// ---- fused gather + GEMM (N x 64) @ (64 x 64) + bias + BN stats --------------
// block 256 = 4 waves; wave wv gathers rows wv*16..wv*16+15 into LDS A-tile,
// then 16x16-thread GEMM. As stride 65: write bank = (lane + r) % 32, conflict-free.
__global__ void ggemm_k(const float* __restrict__ X, int ldx,
                        const int* __restrict__ off, const int* __restrict__ adj,
                        const float* __restrict__ W,    // 64x64 row-major
                        const float* __restrict__ bias,
                        float* __restrict__ T,
                        float* __restrict__ sums) {  // [64] sum, [64] sumsq
    __shared__ float As[64 * 65];   // [k][r]
    __shared__ float Ws[64 * 64];   // [k][n]
    __shared__ float lsum[64], lssq[64];
    int tid = threadIdx.x;
    int rowbase = blockIdx.x * 64;
    int wv = tid >> 6, lane = tid & 63;

    for (int i = tid; i < 1024; i += 256) {
        *(f32x4*)(Ws + i * 4) = *(const f32x4*)(W + i * 4);
    }
    if (tid < 64) { lsum[tid] = 0.f; lssq[tid] = 0.f; }

    // gather 16 rows per wave; lane = feature k
    for (int rr = 0; rr < 16; rr++) {
        int r = wv * 16 + rr;
        int node = rowbase + r;
        if (node >= NN) node = NN - 1;  // dup is harmless; stores guarded below
        As[lane * 65 + r] = gather_row(X, ldx, lane, off, adj, node);
    }
    __syncthreads();

    int ty = tid >> 4, tx = tid & 15;
    float acc[4][4] = {};
    for (int k = 0; k < 64; k++) {
        float a[4], wvv[4];
        #pragma unroll
        for (int i = 0; i < 4; i++) a[i] = As[k * 65 + ty * 4 + i];
        #pragma unroll
        for (int j = 0; j < 4; j++) wvv[j] = Ws[k * 64 + tx * 4 + j];
        #pragma unroll
        for (int i = 0; i < 4; i++)
            #pragma unroll
            for (int j = 0; j < 4; j++) acc[i][j] += a[i] * wvv[j];
    }

    f32x4 bv = *(const f32x4*)(bias + tx * 4);
    float ps[4] = {0.f, 0.f, 0.f, 0.f}, pq[4] = {0.f, 0.f, 0.f, 0.f};
    #pragma unroll
    for (int i = 0; i < 4; i++) {
        int row = rowbase + ty * 4 + i;
        if (row < NN) {
            f32x4 v;
            #pragma unroll
            for (int j = 0; j < 4; j++) {
                v[j] = acc[i][j] + bv[j];
                ps[j] += v[j];
                pq[j] += v[j] * v[j];
            }
            *(f32x4*)(T + (size_t)row * 64 + tx * 4) = v;
        }
    }
    #pragma unroll
    for (int j = 0; j < 4; j++) {
        atomicAdd(&lsum[tx * 4 + j], ps[j]);
        atomicAdd(&lssq[tx * 4 + j], pq[j]);
    }
    __syncthreads();
    if (tid < 64) {
        atomicAdd(&sums[tid], lsum[tid]);
        atomicAdd(&sums[64 + tid], lssq[tid]);
    }
}

// ---- GEMM with fused BN+ReLU on the input: A = relu(Tin*sc + sh), then @W ----
__global__ void gemm64bn_k(const float* __restrict__ Tin,
                           const float* __restrict__ stats,  // [64] sum,[64] sumsq of Tin
                           const float* __restrict__ g,
                           const float* __restrict__ be,
                           const float* __restrict__ W,      // 64x64 row-major
                           const float* __restrict__ bias,
                           float* __restrict__ T,
                           float* __restrict__ sums) {
    __shared__ float As[64 * 72];
    __shared__ float Ws[64 * 64];
    __shared__ float sc[64], sh[64];
    __shared__ float lsum[64], lssq[64];
    int tid = threadIdx.x;
    int rowbase = blockIdx.x * 64;
    if (tid < 64) {
        float m = stats[tid] * (1.0f / NN);
        float var = stats[64 + tid] * (1.0f / NN) - m * m;
        if (var < 0.f) var = 0.f;
        float s = g[tid] * rsqrtf(var + BN_EPS);
        sc[tid] = s;
        sh[tid] = be[tid] - m * s;
        lsum[tid] = 0.f;
        lssq[tid] = 0.f;
    }
    __syncthreads();
    for (int i = tid; i < 64 * 16; i += 256) {
        int r = i >> 4, kq = i & 15;
        int row = rowbase + r;
        if (row >= NN) row = NN - 1;
        f32x4 v = *(const f32x4*)(Tin + (size_t)row * 64 + kq * 4);
        #pragma unroll
        for (int q = 0; q < 4; q++) {
            int k = kq * 4 + q;
            float u = v[q] * sc[k] + sh[k];
            As[k * 72 + r] = u > 0.f ? u : 0.f;
        }
    }
    for (int i = tid; i < 1024; i += 256) {
        *(f32x4*)(Ws + i * 4) = *(const f32x4*)(W + i * 4);
    }
    __syncthreads();

    int ty = tid >> 4, tx = tid & 15;
    float acc[4][4] = {};
    for (int k = 0; k < 64; k++) {
        float a[4], wv[4];
        #pragma unroll
        for (int i = 0; i < 4; i++) a[i] = As[k * 72 + ty * 4 + i];
        #pragma unroll
        for (int j = 0; j < 4; j++) wv[j] = Ws[k * 64 + tx * 4 + j];
        #pragma unroll
        for (int i = 0; i < 4; i++)
            #pragma unroll
            for (int j = 0; j < 4; j++) acc[i][j] += a[i] * wv[j];
    }

    f32x4 bv = *(const f32x4*)(bias + tx * 4);
    float ps[4] = {0.f, 0.f, 0.f, 0.f}, pq[4] = {0.f, 0.f, 0.f, 0.f};
    #pragma unroll
    for (int i = 0; i < 4; i++) {
        int row = rowbase + ty * 4 + i;
        if (row < NN) {
            f32x4 v;
            #pragma unroll
            for (int j = 0; j < 4; j++) {
                v[j] = acc[i][j] + bv[j];
                ps[j] += v[j];
                pq[j] += v[j] * v[j];
            }
            *(f32x4*)(T + (size_t)row * 64 + tx * 4) = v;
        }
    }
    #pragma unroll
    for (int j = 0; j < 4; j++) {
        atomicAdd(&lsum[tx * 4 + j], ps[j]);
        atomicAdd(&lssq[tx * 4 + j], pq[j]);
    }
    __syncthreads();
    if (tid < 64) {
        atomicAdd(&sums[tid], lsum[tid]);
        atomicAdd(&sums[64 + tid], lssq[tid]);
    }
}

// ---------------- BN finalize + apply + ReLU (fp32) -> H (ld 64) --------------
__global__ void bn_k(const float* __restrict__ T, const float* __restrict__ sums,
                     const float* __restrict__ g,
                     const float* __restrict__ be,
                     float* __restrict__ H) {
    __shared__ float sc[64], sh[64];
    int tid = threadIdx.x;
    if (tid < 64) {
        float m = sums[tid] * (1.0f / NN);
        float var = sums[64 + tid] * (1.0f / NN) - m * m;
        if (var < 0.f) var = 0.f;
        float s = g[tid] * rsqrtf(var + BN_EPS);
        sc[tid] = s;
        sh[tid] = be[tid] - m * s;
    }
    __syncthreads();
    int i = blockIdx.x * 256 + tid;  // over NN*16 float4s
    if (i < NN * 16) {
        int row = i >> 4, f = (i & 15) * 4;
        f32x4 v = *(const f32x4*)(T + (size_t)row * 64 + f);
        f32x4 u;
        #pragma unroll
        for (int j = 0; j < 4; j++) {
            float w = v[j] * sc[f + j] + sh[f + j];
            u[j] = w > 0.f ? w : 0.f;
        }
        *(f32x4*)(H + (size_t)row * 64 + f) = u;
    }
}

// ---- final GEMM: [h1 | bn(T2)] (N x 128) @ (128 x 64) + bias -> fp32 out -----
__global__ void gemmfin2_k(const float* __restrict__ H1,   // N x 64 (h1)
                           const float* __restrict__ T2,   // N x 64 pre-BN h2
                           const float* __restrict__ stats,
                           const float* __restrict__ g,
                           const float* __restrict__ be,
                           const float* __restrict__ W,    // 128x64 row-major
                           const float* __restrict__ bias,
                           float* __restrict__ O) {
    __shared__ float As[128 * 72];
    __shared__ float Ws[128 * 64];
    __shared__ float sc[64], sh[64];
    int tid = threadIdx.x;
    int rowbase = blockIdx.x * 64;
    if (tid < 64) {
        float m = stats[tid] * (1.0f / NN);
        float var = stats[64 + tid] * (1.0f / NN) - m * m;
        if (var < 0.f) var = 0.f;
        float s = g[tid] * rsqrtf(var + BN_EPS);
        sc[tid] = s;
        sh[tid] = be[tid] - m * s;
    }
    __syncthreads();
    for (int i = tid; i < 64 * 16; i += 256) {
        int r = i >> 4, kq = i & 15;
        int row = rowbase + r;
        if (row >= NN) row = NN - 1;
        f32x4 v1 = *(const f32x4*)(H1 + (size_t)row * 64 + kq * 4);
        f32x4 v2 = *(const f32x4*)(T2 + (size_t)row * 64 + kq * 4);
        #pragma unroll
        for (int q = 0; q < 4; q++) {
            int k = kq * 4 + q;
            As[k * 72 + r] = v1[q];
            float u = v2[q] * sc[k] + sh[k];
            As[(64 + k) * 72 + r] = u > 0.f ? u : 0.f;
        }
    }
    for (int i = tid; i < 2048; i += 256) {
        *(f32x4*)(Ws + i * 4) = *(const f32x4*)(W + i * 4);
    }
    __syncthreads();

    int ty = tid >> 4, tx = tid & 15;
    float acc[4][4] = {};
    for (int k = 0; k < 128; k++) {
        float a[4], wv[4];
        #pragma unroll
        for (int i = 0; i < 4; i++) a[i] = As[k * 72 + ty * 4 + i];
        #pragma unroll
        for (int j = 0; j < 4; j++) wv[j] = Ws[k * 64 + tx * 4 + j];
        #pragma unroll
        for (int i = 0; i < 4; i++)
            #pragma unroll
            for (int j = 0; j < 4; j++) acc[i][j] += a[i] * wv[j];
    }

    f32x4 bv = *(const f32x4*)(bias + tx * 4);
    #pragma unroll
    for (int i = 0; i < 4; i++) {
        int row = rowbase + ty * 4 + i;
        if (row < NN) {
            f32x4 v;
            #pragma unroll
            for (int j = 0; j < 4; j++) v[j] = acc[i][j] + bv[j];
            *(f32x4*)(O + (size_t)row * 64 + tx * 4) = v;
        }
    }
}

// ---------------- launch ----------------
extern "C" void kernel_launch(void* const* d_in, const int* in_sizes, int n_in,
                              void* d_out, int out_size, void* d_ws, size_t ws_size,
                              hipStream_t stream) {
    const float* x   = (const float*)d_in[0];
    const int*   ei  = (const int*)d_in[1];
    const float* w0a = (const float*)d_in[2];
    const float* b0a = (const float*)d_in[3];
    const float* g0a = (const float*)d_in[4];
    const float* be0a= (const float*)d_in[5];
    const float* w0b = (const float*)d_in[6];
    const float* b0b = (const float*)d_in[7];
    const float* g0b = (const float*)d_in[8];
    const float* be0b= (const float*)d_in[9];
    const float* w1a = (const float*)d_in[10];
    const float* b1a = (const float*)d_in[11];
    const float* g1a = (const float*)d_in[12];
    const float* be1a= (const float*)d_in[13];
    const float* w1b = (const float*)d_in[14];
    const float* b1b = (const float*)d_in[15];
    const float* g1b = (const float*)d_in[16];
    const float* be1b= (const float*)d_in[17];
    const float* lw  = (const float*)d_in[18];
    const float* lb  = (const float*)d_in[19];
    float* out = (float*)d_out;
    (void)in_sizes; (void)n_in; (void)out_size; (void)ws_size;

    char* wsb = (char*)d_ws;
    size_t o = 0;
    auto alloc = [&](size_t bytes) -> char* {
        char* p = wsb + o;
        o += (bytes + 255) & ~(size_t)255;
        return p;
    };
    int* bcnt = (int*)alloc(256 * 4);         // zeroed below (pads to 1024B)
    float* sums = (float*)alloc(512 * 4);     // zeroed below (4 sets of 128)
    int* bbase = (int*)alloc(257 * 4);
    int* bres = (int*)alloc(256 * 4);
    int* off = (int*)alloc((NN + 1) * 4);
    int* adj = (int*)alloc(NE * 4);
    int* ebuf = (int*)alloc(NE * 4);
    float* T   = (float*)alloc((size_t)NN * 64 * 4);
    float* T2  = (float*)alloc((size_t)NN * 64 * 4);
    float* HC  = (float*)alloc((size_t)NN * 64 * 4);  // h1 only

    const int* src = ei;
    const int* dst = ei + NE;

    // zero bcnt (1024 B) + sums (2048 B) = 768 ints contiguous
    zero_k<<<3, 256, 0, stream>>>((int*)d_ws, 768);
    bhist_k<<<NCH, 256, 0, stream>>>(dst, bcnt);
    bscan_k<<<1, 256, 0, stream>>>(bcnt, bbase, bres, off);
    bscatter_k<<<NCH, 256, 0, stream>>>(src, dst, bres, ebuf);
    csr_k<<<NBK, 256, 0, stream>>>(bbase, ebuf, off, adj);

    const int mgrid = (NN + 63) / 64;          // 782
    const int agrid = (NN * 16 + 255) / 256;   // 3125 (float4 granularity)

    // ---- layer 0 ----
    ggemm_k<<<mgrid, 256, 0, stream>>>(x, 64, off, adj, w0a, b0a, T, sums + 0);
    gemm64bn_k<<<mgrid, 256, 0, stream>>>(T, sums + 0, g0a, be0a, w0b, b0b, T2, sums + 128);
    bn_k<<<agrid, 256, 0, stream>>>(T2, sums + 128, g0b, be0b, HC);           // h1

    // ---- layer 1 ----
    ggemm_k<<<mgrid, 256, 0, stream>>>(HC, 64, off, adj, w1a, b1a, T, sums + 256);
    gemm64bn_k<<<mgrid, 256, 0, stream>>>(T, sums + 256, g1a, be1a, w1b, b1b, T2, sums + 384);

    // ---- JK cat + final linear (h2's BN fused into A-staging) ----
    gemmfin2_k<<<mgrid, 256, 0, stream>>>(HC, T2, sums + 384, g1b, be1b, lw, lb, out);
}

// Round 8
// 355.170 us; speedup vs baseline: 1.0700x; 1.0700x over previous
//
#include <hip/hip_runtime.h>
#include <hip/hip_bf16.h>

#define NN 50000
#define NE 800000
#define BN_EPS 1e-5f
#define CHUNK 8192
#define NCH 98     // ceil(NE / CHUNK)
#define NBK 196    // ceil(NN / 256) dst-buckets

typedef __attribute__((ext_vector_type(4))) float f32x4;
typedef __attribute__((ext_vector_type(4))) short s16x4;

__device__ __forceinline__ float bf2f(__hip_bfloat16 v) { return __bfloat162float(v); }

// ---------------- utility: zero ints (bcnt + sums) ----------------
__global__ void zero_k(int* __restrict__ p, int n) {
    int i = blockIdx.x * 256 + threadIdx.x;
    if (i < n) p[i] = 0;
}

// ---------------- fp32 -> bf16 convert (row-major N x 64) ----------------
__global__ void cvt_k(const float* __restrict__ X, __hip_bfloat16* __restrict__ Xb) {
    int i = blockIdx.x * 256 + threadIdx.x;  // over NN*16 float4s
    if (i < NN * 16) {
        f32x4 v = *(const f32x4*)(X + (size_t)i * 4);
        s16x4 ov;
        #pragma unroll
        for (int j = 0; j < 4; j++) {
            __hip_bfloat16 b = __float2bfloat16(v[j]);
            ov[j] = __builtin_bit_cast(short, b);
        }
        *(s16x4*)((short*)Xb + (size_t)i * 4) = ov;
    }
}

// ---------------- bucket histogram: bucket = dst >> 8 ----------------
__global__ void bhist_k(const int* __restrict__ dst, int* __restrict__ bcnt) {
    __shared__ int c[256];
    int t = threadIdx.x;
    c[t] = 0;
    __syncthreads();
    int base = blockIdx.x * CHUNK;
    int n = NE - base; if (n > CHUNK) n = CHUNK;
    for (int i = t; i < n; i += 256) atomicAdd(&c[dst[base + i] >> 8], 1);
    __syncthreads();
    if (c[t]) atomicAdd(&bcnt[t], c[t]);
}

// ---------------- scan bucket counts -> bbase/bres ----------------
__global__ void bscan_k(const int* __restrict__ bcnt, int* __restrict__ bbase,
                        int* __restrict__ bres, int* __restrict__ off) {
    __shared__ int s[256];
    int t = threadIdx.x;
    int v = bcnt[t];
    s[t] = v;
    __syncthreads();
    for (int d = 1; d < 256; d <<= 1) {
        int u = (t >= d) ? s[t - d] : 0;
        __syncthreads();
        s[t] += u;
        __syncthreads();
    }
    int ex = s[t] - v;
    bbase[t] = ex;
    bres[t] = ex;
    if (t == 0) { bbase[256] = NE; off[NN] = NE; }
}

// ---------------- bucket scatter: chunk -> bucket-ordered global ebuf ---------
// packed int: src (16b) | dst&255 (8b) | bucket (8b)
__global__ void bscatter_k(const int* __restrict__ src, const int* __restrict__ dst,
                           int* __restrict__ bres, int* __restrict__ ebuf) {
    __shared__ int cnt[256], loff[256], lcur[256], gst[256], sc[256];
    __shared__ int packed[CHUNK];
    int t = threadIdx.x;
    cnt[t] = 0;
    __syncthreads();
    int base = blockIdx.x * CHUNK;
    int n = NE - base; if (n > CHUNK) n = CHUNK;
    for (int i = t; i < n; i += 256) atomicAdd(&cnt[dst[base + i] >> 8], 1);
    __syncthreads();
    sc[t] = cnt[t];
    __syncthreads();
    for (int d = 1; d < 256; d <<= 1) {
        int u = (t >= d) ? sc[t - d] : 0;
        __syncthreads();
        sc[t] += u;
        __syncthreads();
    }
    loff[t] = sc[t] - cnt[t];
    lcur[t] = loff[t];
    __syncthreads();
    for (int i = t; i < n; i += 256) {
        int d = dst[base + i];
        int b = d >> 8;
        int p = atomicAdd(&lcur[b], 1);
        packed[p] = src[base + i] | ((d & 255) << 16) | (b << 24);
    }
    __syncthreads();
    if (cnt[t]) gst[t] = atomicAdd(&bres[t], cnt[t]);
    __syncthreads();
    for (int i = t; i < n; i += 256) {
        int v = packed[i];
        int b = (v >> 24) & 255;
        ebuf[gst[b] + i - loff[b]] = v & 0xFFFFFF;
    }
}

// ---------------- per-bucket CSR: off[] + adj[] (all writes XCD-local) --------
__global__ void csr_k(const int* __restrict__ bbase, const int* __restrict__ ebuf,
                      int* __restrict__ off, int* __restrict__ adj) {
    __shared__ int cnt[256], loff[256], lcur[256], sc[256];
    int b = blockIdx.x, t = threadIdx.x;
    int s0 = bbase[b], s1 = bbase[b + 1];
    int n = s1 - s0;
    cnt[t] = 0;
    __syncthreads();
    for (int i = t; i < n; i += 256) atomicAdd(&cnt[(ebuf[s0 + i] >> 16) & 255], 1);
    __syncthreads();
    sc[t] = cnt[t];
    __syncthreads();
    for (int d = 1; d < 256; d <<= 1) {
        int u = (t >= d) ? sc[t - d] : 0;
        __syncthreads();
        sc[t] += u;
        __syncthreads();
    }
    loff[t] = sc[t] - cnt[t];
    lcur[t] = loff[t];
    int node = b * 256 + t;
    if (node < NN) off[node] = s0 + loff[t];
    __syncthreads();
    for (int i = t; i < n; i += 256) {
        int v = ebuf[s0 + i];
        int p = atomicAdd(&lcur[(v >> 16) & 255], 1);
        adj[s0 + p] = v & 0xFFFF;
    }
}

// ---------------- aggregation over bf16 X: AGG[i] = X[i] + sum X[j]  ----------
// one wave per node, lane = feature (64 feats); 8-deep load pipelining
__global__ void gather_k(const __hip_bfloat16* __restrict__ X,
                         const int* __restrict__ off, const int* __restrict__ adj,
                         float* __restrict__ AGG) {
    int node = blockIdx.x * 4 + (threadIdx.x >> 6);
    int lane = threadIdx.x & 63;
    if (node >= NN) return;
    float acc = bf2f(X[(size_t)node * 64 + lane]);
    int s = off[node], e = off[node + 1];
    int p = s;
    for (; p + 8 <= e; p += 8) {
        int j0 = adj[p + 0], j1 = adj[p + 1], j2 = adj[p + 2], j3 = adj[p + 3];
        int j4 = adj[p + 4], j5 = adj[p + 5], j6 = adj[p + 6], j7 = adj[p + 7];
        float v0 = bf2f(X[(size_t)j0 * 64 + lane]);
        float v1 = bf2f(X[(size_t)j1 * 64 + lane]);
        float v2 = bf2f(X[(size_t)j2 * 64 + lane]);
        float v3 = bf2f(X[(size_t)j3 * 64 + lane]);
        float v4 = bf2f(X[(size_t)j4 * 64 + lane]);
        float v5 = bf2f(X[(size_t)j5 * 64 + lane]);
        float v6 = bf2f(X[(size_t)j6 * 64 + lane]);
        float v7 = bf2f(X[(size_t)j7 * 64 + lane]);
        acc += ((v0 + v1) + (v2 + v3)) + ((v4 + v5) + (v6 + v7));
    }
    if (p + 4 <= e) {
        int j0 = adj[p + 0], j1 = adj[p + 1], j2 = adj[p + 2], j3 = adj[p + 3];
        float v0 = bf2f(X[(size_t)j0 * 64 + lane]);
        float v1 = bf2f(X[(size_t)j1 * 64 + lane]);
        float v2 = bf2f(X[(size_t)j2 * 64 + lane]);
        float v3 = bf2f(X[(size_t)j3 * 64 + lane]);
        acc += (v0 + v1) + (v2 + v3);
        p += 4;
    }
    for (; p < e; p++) acc += bf2f(X[(size_t)adj[p] * 64 + lane]);
    AGG[(size_t)node * 64 + lane] = acc;
}

// ---------------- GEMM (N x 64) @ (64 x 64) + bias, fp32, + BN stats ----------
__global__ void gemm64_k(const float* __restrict__ A,
                         const float* __restrict__ W,    // 64x64 row-major
                         const float* __restrict__ bias,
                         float* __restrict__ T,
                         float* __restrict__ sums) {  // [64] sum, [64] sumsq
    __shared__ float As[64 * 72];   // [k][r], pad 72
    __shared__ float Ws[64 * 64];   // [k][n]
    __shared__ float lsum[64], lssq[64];
    int tid = threadIdx.x;
    int rowbase = blockIdx.x * 64;
    for (int i = tid; i < 64 * 16; i += 256) {
        int r = i >> 4, kq = i & 15;
        int row = rowbase + r;
        if (row >= NN) row = NN - 1;
        f32x4 v = *(const f32x4*)(A + (size_t)row * 64 + kq * 4);
        #pragma unroll
        for (int q = 0; q < 4; q++) As[(kq * 4 + q) * 72 + r] = v[q];
    }
    for (int i = tid; i < 1024; i += 256) {
        *(f32x4*)(Ws + i * 4) = *(const f32x4*)(W + i * 4);
    }
    if (tid < 64) { lsum[tid] = 0.f; lssq[tid] = 0.f; }
    __syncthreads();

    int ty = tid >> 4, tx = tid & 15;
    float acc[4][4] = {};
    for (int k = 0; k < 64; k++) {
        float a[4], wv[4];
        #pragma unroll
        for (int i = 0; i < 4; i++) a[i] = As[k * 72 + ty * 4 + i];
        #pragma unroll
        for (int j = 0; j < 4; j++) wv[j] = Ws[k * 64 + tx * 4 + j];
        #pragma unroll
        for (int i = 0; i < 4; i++)
            #pragma unroll
            for (int j = 0; j < 4; j++) acc[i][j] += a[i] * wv[j];
    }

    f32x4 bv = *(const f32x4*)(bias + tx * 4);
    float ps[4] = {0.f, 0.f, 0.f, 0.f}, pq[4] = {0.f, 0.f, 0.f, 0.f};
    #pragma unroll
    for (int i = 0; i < 4; i++) {
        int row = rowbase + ty * 4 + i;
        if (row < NN) {
            f32x4 v;
            #pragma unroll
            for (int j = 0; j < 4; j++) {
                v[j] = acc[i][j] + bv[j];
                ps[j] += v[j];
                pq[j] += v[j] * v[j];
            }
            *(f32x4*)(T + (size_t)row * 64 + tx * 4) = v;
        }
    }
    #pragma unroll
    for (int j = 0; j < 4; j++) {
        atomicAdd(&lsum[tx * 4 + j], ps[j]);
        atomicAdd(&lssq[tx * 4 + j], pq[j]);
    }
    __syncthreads();
    if (tid < 64) {
        atomicAdd(&sums[tid], lsum[tid]);
        atomicAdd(&sums[64 + tid], lssq[tid]);
    }
}

// ---- GEMM with fused BN+ReLU on the input: A = relu(Tin*sc + sh), then @W ----
__global__ void gemm64bn_k(const float* __restrict__ Tin,
                           const float* __restrict__ stats,  // [64] sum,[64] sumsq of Tin
                           const float* __restrict__ g,
                           const float* __restrict__ be,
                           const float* __restrict__ W,      // 64x64 row-major
                           const float* __restrict__ bias,
                           float* __restrict__ T,
                           float* __restrict__ sums) {
    __shared__ float As[64 * 72];
    __shared__ float Ws[64 * 64];
    __shared__ float sc[64], sh[64];
    __shared__ float lsum[64], lssq[64];
    int tid = threadIdx.x;
    int rowbase = blockIdx.x * 64;
    if (tid < 64) {
        float m = stats[tid] * (1.0f / NN);
        float var = stats[64 + tid] * (1.0f / NN) - m * m;
        if (var < 0.f) var = 0.f;
        float s = g[tid] * rsqrtf(var + BN_EPS);
        sc[tid] = s;
        sh[tid] = be[tid] - m * s;
        lsum[tid] = 0.f;
        lssq[tid] = 0.f;
    }
    __syncthreads();
    for (int i = tid; i < 64 * 16; i += 256) {
        int r = i >> 4, kq = i & 15;
        int row = rowbase + r;
        if (row >= NN) row = NN - 1;
        f32x4 v = *(const f32x4*)(Tin + (size_t)row * 64 + kq * 4);
        #pragma unroll
        for (int q = 0; q < 4; q++) {
            int k = kq * 4 + q;
            float u = v[q] * sc[k] + sh[k];
            As[k * 72 + r] = u > 0.f ? u : 0.f;
        }
    }
    for (int i = tid; i < 1024; i += 256) {
        *(f32x4*)(Ws + i * 4) = *(const f32x4*)(W + i * 4);
    }
    __syncthreads();

    int ty = tid >> 4, tx = tid & 15;
    float acc[4][4] = {};
    for (int k = 0; k < 64; k++) {
        float a[4], wv[4];
        #pragma unroll
        for (int i = 0; i < 4; i++) a[i] = As[k * 72 + ty * 4 + i];
        #pragma unroll
        for (int j = 0; j < 4; j++) wv[j] = Ws[k * 64 + tx * 4 + j];
        #pragma unroll
        for (int i = 0; i < 4; i++)
            #pragma unroll
            for (int j = 0; j < 4; j++) acc[i][j] += a[i] * wv[j];
    }

    f32x4 bv = *(const f32x4*)(bias + tx * 4);
    float ps[4] = {0.f, 0.f, 0.f, 0.f}, pq[4] = {0.f, 0.f, 0.f, 0.f};
    #pragma unroll
    for (int i = 0; i < 4; i++) {
        int row = rowbase + ty * 4 + i;
        if (row < NN) {
            f32x4 v;
            #pragma unroll
            for (int j = 0; j < 4; j++) {
                v[j] = acc[i][j] + bv[j];
                ps[j] += v[j];
                pq[j] += v[j] * v[j];
            }
            *(f32x4*)(T + (size_t)row * 64 + tx * 4) = v;
        }
    }
    #pragma unroll
    for (int j = 0; j < 4; j++) {
        atomicAdd(&lsum[tx * 4 + j], ps[j]);
        atomicAdd(&lssq[tx * 4 + j], pq[j]);
    }
    __syncthreads();
    if (tid < 64) {
        atomicAdd(&sums[tid], lsum[tid]);
        atomicAdd(&sums[64 + tid], lssq[tid]);
    }
}

// ---- BN finalize + apply + ReLU -> H (fp32, for final GEMM) + Hb (bf16, for gather)
__global__ void bn_k(const float* __restrict__ T, const float* __restrict__ sums,
                     const float* __restrict__ g,
                     const float* __restrict__ be,
                     float* __restrict__ H, __hip_bfloat16* __restrict__ Hb) {
    __shared__ float sc[64], sh[64];
    int tid = threadIdx.x;
    if (tid < 64) {
        float m = sums[tid] * (1.0f / NN);
        float var = sums[64 + tid] * (1.0f / NN) - m * m;
        if (var < 0.f) var = 0.f;
        float s = g[tid] * rsqrtf(var + BN_EPS);
        sc[tid] = s;
        sh[tid] = be[tid] - m * s;
    }
    __syncthreads();
    int i = blockIdx.x * 256 + tid;  // over NN*16 float4s
    if (i < NN * 16) {
        int row = i >> 4, f = (i & 15) * 4;
        f32x4 v = *(const f32x4*)(T + (size_t)row * 64 + f);
        f32x4 u;
        s16x4 ub;
        #pragma unroll
        for (int j = 0; j < 4; j++) {
            float w = v[j] * sc[f + j] + sh[f + j];
            u[j] = w > 0.f ? w : 0.f;
            __hip_bfloat16 b = __float2bfloat16(u[j]);
            ub[j] = __builtin_bit_cast(short, b);
        }
        *(f32x4*)(H + (size_t)row * 64 + f) = u;
        *(s16x4*)((short*)Hb + (size_t)row * 64 + f) = ub;
    }
}

// ---- final GEMM: [h1 | bn(T2)] (N x 128) @ (128 x 64) + bias -> fp32 out -----
__global__ void gemmfin2_k(const float* __restrict__ H1,   // N x 64 (h1)
                           const float* __restrict__ T2,   // N x 64 pre-BN h2
                           const float* __restrict__ stats,
                           const float* __restrict__ g,
                           const float* __restrict__ be,
                           const float* __restrict__ W,    // 128x64 row-major
                           const float* __restrict__ bias,
                           float* __restrict__ O) {
    __shared__ float As[128 * 72];
    __shared__ float Ws[128 * 64];
    __shared__ float sc[64], sh[64];
    int tid = threadIdx.x;
    int rowbase = blockIdx.x * 64;
    if (tid < 64) {
        float m = stats[tid] * (1.0f / NN);
        float var = stats[64 + tid] * (1.0f / NN) - m * m;
        if (var < 0.f) var = 0.f;
        float s = g[tid] * rsqrtf(var + BN_EPS);
        sc[tid] = s;
        sh[tid] = be[tid] - m * s;
    }
    __syncthreads();
    for (int i = tid; i < 64 * 16; i += 256) {
        int r = i >> 4, kq = i & 15;
        int row = rowbase + r;
        if (row >= NN) row = NN - 1;
        f32x4 v1 = *(const f32x4*)(H1 + (size_t)row * 64 + kq * 4);
        f32x4 v2 = *(const f32x4*)(T2 + (size_t)row * 64 + kq * 4);
        #pragma unroll
        for (int q = 0; q < 4; q++) {
            int k = kq * 4 + q;
            As[k * 72 + r] = v1[q];
            float u = v2[q] * sc[k] + sh[k];
            As[(64 + k) * 72 + r] = u > 0.f ? u : 0.f;
        }
    }
    for (int i = tid; i < 2048; i += 256) {
        *(f32x4*)(Ws + i * 4) = *(const f32x4*)(W + i * 4);
    }
    __syncthreads();

    int ty = tid >> 4, tx = tid & 15;
    float acc[4][4] = {};
    for (int k = 0; k < 128; k++) {
        float a[4], wv[4];
        #pragma unroll
        for (int i = 0; i < 4; i++) a[i] = As[k * 72 + ty * 4 + i];
        #pragma unroll
        for (int j = 0; j < 4; j++) wv[j] = Ws[k * 64 + tx * 4 + j];
        #pragma unroll
        for (int i = 0; i < 4; i++)
            #pragma unroll
            for (int j = 0; j < 4; j++) acc[i][j] += a[i] * wv[j];
    }

    f32x4 bv = *(const f32x4*)(bias + tx * 4);
    #pragma unroll
    for (int i = 0; i < 4; i++) {
        int row = rowbase + ty * 4 + i;
        if (row < NN) {
            f32x4 v;
            #pragma unroll
            for (int j = 0; j < 4; j++) v[j] = acc[i][j] + bv[j];
            *(f32x4*)(O + (size_t)row * 64 + tx * 4) = v;
        }
    }
}

// ---------------- launch ----------------
extern "C" void kernel_launch(void* const* d_in, const int* in_sizes, int n_in,
                              void* d_out, int out_size, void* d_ws, size_t ws_size,
                              hipStream_t stream) {
    const float* x   = (const float*)d_in[0];
    const int*   ei  = (const int*)d_in[1];
    const float* w0a = (const float*)d_in[2];
    const float* b0a = (const float*)d_in[3];
    const float* g0a = (const float*)d_in[4];
    const float* be0a= (const float*)d_in[5];
    const float* w0b = (const float*)d_in[6];
    const float* b0b = (const float*)d_in[7];
    const float* g0b = (const float*)d_in[8];
    const float* be0b= (const float*)d_in[9];
    const float* w1a = (const float*)d_in[10];
    const float* b1a = (const float*)d_in[11];
    const float* g1a = (const float*)d_in[12];
    const float* be1a= (const float*)d_in[13];
    const float* w1b = (const float*)d_in[14];
    const float* b1b = (const float*)d_in[15];
    const float* g1b = (const float*)d_in[16];
    const float* be1b= (const float*)d_in[17];
    const float* lw  = (const float*)d_in[18];
    const float* lb  = (const float*)d_in[19];
    float* out = (float*)d_out;
    (void)in_sizes; (void)n_in; (void)out_size; (void)ws_size;

    char* wsb = (char*)d_ws;
    size_t o = 0;
    auto alloc = [&](size_t bytes) -> char* {
        char* p = wsb + o;
        o += (bytes + 255) & ~(size_t)255;
        return p;
    };
    int* bcnt = (int*)alloc(256 * 4);         // zeroed below (pads to 1024B)
    float* sums = (float*)alloc(512 * 4);     // zeroed below (4 sets of 128)
    int* bbase = (int*)alloc(257 * 4);
    int* bres = (int*)alloc(256 * 4);
    int* off = (int*)alloc((NN + 1) * 4);
    int* adj = (int*)alloc(NE * 4);
    int* ebuf = (int*)alloc(NE * 4);
    float* AGG = (float*)alloc((size_t)NN * 64 * 4);
    float* T   = (float*)alloc((size_t)NN * 64 * 4);
    float* T2  = (float*)alloc((size_t)NN * 64 * 4);
    float* HC  = (float*)alloc((size_t)NN * 64 * 4);                 // h1 fp32
    __hip_bfloat16* Xb  = (__hip_bfloat16*)alloc((size_t)NN * 64 * 2);  // x bf16
    __hip_bfloat16* HCb = (__hip_bfloat16*)alloc((size_t)NN * 64 * 2);  // h1 bf16

    const int* src = ei;
    const int* dst = ei + NE;

    // zero bcnt (1024 B) + sums (2048 B) = 768 ints contiguous
    zero_k<<<3, 256, 0, stream>>>((int*)d_ws, 768);
    bhist_k<<<NCH, 256, 0, stream>>>(dst, bcnt);
    bscan_k<<<1, 256, 0, stream>>>(bcnt, bbase, bres, off);
    bscatter_k<<<NCH, 256, 0, stream>>>(src, dst, bres, ebuf);
    csr_k<<<NBK, 256, 0, stream>>>(bbase, ebuf, off, adj);

    const int ggrid = NN / 4;                  // 12500 (wave per node)
    const int mgrid = (NN + 63) / 64;          // 782
    const int agrid = (NN * 16 + 255) / 256;   // 3125 (float4 granularity)

    cvt_k<<<agrid, 256, 0, stream>>>(x, Xb);

    // ---- layer 0 ----
    gather_k<<<ggrid, 256, 0, stream>>>(Xb, off, adj, AGG);
    gemm64_k<<<mgrid, 256, 0, stream>>>(AGG, w0a, b0a, T, sums + 0);
    gemm64bn_k<<<mgrid, 256, 0, stream>>>(T, sums + 0, g0a, be0a, w0b, b0b, T2, sums + 128);
    bn_k<<<agrid, 256, 0, stream>>>(T2, sums + 128, g0b, be0b, HC, HCb);      // h1

    // ---- layer 1 ----
    gather_k<<<ggrid, 256, 0, stream>>>(HCb, off, adj, AGG);
    gemm64_k<<<mgrid, 256, 0, stream>>>(AGG, w1a, b1a, T, sums + 256);
    gemm64bn_k<<<mgrid, 256, 0, stream>>>(T, sums + 256, g1a, be1a, w1b, b1b, T2, sums + 384);

    // ---- JK cat + final linear (h2's BN fused into A-staging) ----
    gemmfin2_k<<<mgrid, 256, 0, stream>>>(HC, T2, sums + 384, g1b, be1b, lw, lb, out);
}

// Round 9
// 348.347 us; speedup vs baseline: 1.0909x; 1.0196x over previous
//
#include <hip/hip_runtime.h>
#include <hip/hip_bf16.h>

#define NN 50000
#define NE 800000
#define BN_EPS 1e-5f
#define CHUNK 4096
#define NCH 196    // ceil(NE / CHUNK) = 196 (196*4096 = 802816)
#define NBK 196    // ceil(NN / 256) dst-buckets

typedef __attribute__((ext_vector_type(4))) float f32x4;
typedef __attribute__((ext_vector_type(8))) short s16x8;   // 8 bf16 = MFMA A/B frag
typedef __attribute__((ext_vector_type(4))) short s16x4;

__device__ __forceinline__ float bf2f(__hip_bfloat16 v) { return __bfloat162float(v); }
__device__ __forceinline__ short f2bs(float v) {
    __hip_bfloat16 b = __float2bfloat16(v);
    return __builtin_bit_cast(short, b);
}

// ---- prep: [0,196) bhist chunks -> part; [196,3321) cvt x->Xb; [3321,3326) W^T->bf16
__global__ void prep_k(const int* __restrict__ dst, int* __restrict__ part,
                       const float* __restrict__ x, __hip_bfloat16* __restrict__ Xb,
                       const float* __restrict__ w0a, const float* __restrict__ w0b,
                       const float* __restrict__ w1a, const float* __restrict__ w1b,
                       const float* __restrict__ lw,
                       short* __restrict__ Wt0a, short* __restrict__ Wt0b,
                       short* __restrict__ Wt1a, short* __restrict__ Wt1b,
                       short* __restrict__ Wtf) {
    int b = blockIdx.x, t = threadIdx.x;
    if (b < NCH) {
        __shared__ int c[256];
        c[t] = 0;
        __syncthreads();
        int base = b * CHUNK;
        int n = NE - base; if (n > CHUNK) n = CHUNK;
        for (int i = t; i < n; i += 256) atomicAdd(&c[dst[base + i] >> 8], 1);
        __syncthreads();
        part[b * 256 + t] = c[t];
    } else if (b < 196 + 3125) {
        int i = (b - 196) * 256 + t;  // over NN*16 = 800000 float4s
        if (i < NN * 16) {
            f32x4 v = *(const f32x4*)(x + (size_t)i * 4);
            s16x4 ov;
            #pragma unroll
            for (int j = 0; j < 4; j++) ov[j] = f2bs(v[j]);
            *(s16x4*)((short*)Xb + (size_t)i * 4) = ov;
        }
    } else {
        int wb = b - 3321;
        if (wb < 4) {
            const float* W = wb == 0 ? w0a : wb == 1 ? w0b : wb == 2 ? w1a : w1b;
            short* Wt = wb == 0 ? Wt0a : wb == 1 ? Wt0b : wb == 2 ? Wt1a : Wt1b;
            for (int e = t; e < 4096; e += 256) {
                int k = e >> 6, n = e & 63;
                Wt[n * 64 + k] = f2bs(W[e]);
            }
        } else {
            for (int e = t; e < 8192; e += 256) {
                int k = e >> 6, n = e & 63;
                Wtf[n * 128 + k] = f2bs(lw[e]);
            }
        }
    }
}

// ---- scan bucket totals (sum part over chunks) -> bbase/bres; zero sums -------
__global__ void bscan_k(const int* __restrict__ part, int* __restrict__ bbase,
                        int* __restrict__ bres, int* __restrict__ off,
                        float* __restrict__ sums) {
    __shared__ int s[256];
    int t = threadIdx.x;
    int v = 0;
    for (int c = 0; c < NCH; c++) v += part[c * 256 + t];
    s[t] = v;
    __syncthreads();
    for (int d = 1; d < 256; d <<= 1) {
        int u = (t >= d) ? s[t - d] : 0;
        __syncthreads();
        s[t] += u;
        __syncthreads();
    }
    int ex = s[t] - v;
    bbase[t] = ex;
    bres[t] = ex;
    if (t == 0) { bbase[256] = NE; off[NN] = NE; }
    sums[t] = 0.f; sums[256 + t] = 0.f;  // 512 floats total
}

// ---- bucket scatter: chunk -> bucket-ordered ebuf (coalesced writes) ----------
// packed int: src (16b) | dst&255 (8b) | bucket (8b)
__global__ void bscatter_k(const int* __restrict__ src, const int* __restrict__ dst,
                           int* __restrict__ bres, int* __restrict__ ebuf) {
    __shared__ int cnt[256], loff[256], lcur[256], gst[256], sc[256];
    __shared__ int packed[CHUNK];
    int t = threadIdx.x;
    cnt[t] = 0;
    __syncthreads();
    int base = blockIdx.x * CHUNK;
    int n = NE - base; if (n > CHUNK) n = CHUNK;
    for (int i = t; i < n; i += 256) atomicAdd(&cnt[dst[base + i] >> 8], 1);
    __syncthreads();
    sc[t] = cnt[t];
    __syncthreads();
    for (int d = 1; d < 256; d <<= 1) {
        int u = (t >= d) ? sc[t - d] : 0;
        __syncthreads();
        sc[t] += u;
        __syncthreads();
    }
    loff[t] = sc[t] - cnt[t];
    lcur[t] = loff[t];
    __syncthreads();
    for (int i = t; i < n; i += 256) {
        int d = dst[base + i];
        int b = d >> 8;
        int p = atomicAdd(&lcur[b], 1);
        packed[p] = src[base + i] | ((d & 255) << 16) | (b << 24);
    }
    __syncthreads();
    if (cnt[t]) gst[t] = atomicAdd(&bres[t], cnt[t]);
    __syncthreads();
    for (int i = t; i < n; i += 256) {
        int v = packed[i];
        int b = (v >> 24) & 255;
        ebuf[gst[b] + i - loff[b]] = v & 0xFFFFFF;
    }
}

// ---- per-bucket CSR: off[] + adj[] --------------------------------------------
__global__ void csr_k(const int* __restrict__ bbase, const int* __restrict__ ebuf,
                      int* __restrict__ off, int* __restrict__ adj) {
    __shared__ int cnt[256], loff[256], lcur[256], sc[256];
    int b = blockIdx.x, t = threadIdx.x;
    int s0 = bbase[b], s1 = bbase[b + 1];
    int n = s1 - s0;
    cnt[t] = 0;
    __syncthreads();
    for (int i = t; i < n; i += 256) atomicAdd(&cnt[(ebuf[s0 + i] >> 16) & 255], 1);
    __syncthreads();
    sc[t] = cnt[t];
    __syncthreads();
    for (int d = 1; d < 256; d <<= 1) {
        int u = (t >= d) ? sc[t - d] : 0;
        __syncthreads();
        sc[t] += u;
        __syncthreads();
    }
    loff[t] = sc[t] - cnt[t];
    lcur[t] = loff[t];
    int node = b * 256 + t;
    if (node < NN) off[node] = s0 + loff[t];
    __syncthreads();
    for (int i = t; i < n; i += 256) {
        int v = ebuf[s0 + i];
        int p = atomicAdd(&lcur[(v >> 16) & 255], 1);
        adj[s0 + p] = v & 0xFFFF;
    }
}

// ---- aggregation over bf16 X -> bf16 AGG; wave per node, lane = feature -------
__global__ void gather_k(const __hip_bfloat16* __restrict__ X,
                         const int* __restrict__ off, const int* __restrict__ adj,
                         __hip_bfloat16* __restrict__ AGG) {
    int node = blockIdx.x * 4 + (threadIdx.x >> 6);
    int lane = threadIdx.x & 63;
    if (node >= NN) return;
    float acc = bf2f(X[(size_t)node * 64 + lane]);
    int s = off[node], e = off[node + 1];
    int p = s;
    for (; p + 8 <= e; p += 8) {
        int j0 = adj[p + 0], j1 = adj[p + 1], j2 = adj[p + 2], j3 = adj[p + 3];
        int j4 = adj[p + 4], j5 = adj[p + 5], j6 = adj[p + 6], j7 = adj[p + 7];
        float v0 = bf2f(X[(size_t)j0 * 64 + lane]);
        float v1 = bf2f(X[(size_t)j1 * 64 + lane]);
        float v2 = bf2f(X[(size_t)j2 * 64 + lane]);
        float v3 = bf2f(X[(size_t)j3 * 64 + lane]);
        float v4 = bf2f(X[(size_t)j4 * 64 + lane]);
        float v5 = bf2f(X[(size_t)j5 * 64 + lane]);
        float v6 = bf2f(X[(size_t)j6 * 64 + lane]);
        float v7 = bf2f(X[(size_t)j7 * 64 + lane]);
        acc += ((v0 + v1) + (v2 + v3)) + ((v4 + v5) + (v6 + v7));
    }
    if (p + 4 <= e) {
        int j0 = adj[p + 0], j1 = adj[p + 1], j2 = adj[p + 2], j3 = adj[p + 3];
        float v0 = bf2f(X[(size_t)j0 * 64 + lane]);
        float v1 = bf2f(X[(size_t)j1 * 64 + lane]);
        float v2 = bf2f(X[(size_t)j2 * 64 + lane]);
        float v3 = bf2f(X[(size_t)j3 * 64 + lane]);
        acc += (v0 + v1) + (v2 + v3);
        p += 4;
    }
    for (; p < e; p++) acc += bf2f(X[(size_t)adj[p] * 64 + lane]);
    AGG[(size_t)node * 64 + lane] = __float2bfloat16(acc);
}

// ---- MFMA GEMM core: wave handles 16 rows x 64 cols, K=64 ---------------------
// A-frag: lane L -> A[row = base + (L&15)][k = quad*8 + j]  (16B global load)
// B-frag: lane L -> W[k = quad*8 + j][n = nt*16 + (L&15)] via Wt[n*64 + k]
// C/D:    lane L, reg r -> D[row = quad*4 + r][col = nt*16 + (L&15)]  (m89-verified)

// GEMM (A bf16 direct) + bias + BN stats -> T fp32
__global__ void gemm_a_k(const __hip_bfloat16* __restrict__ Ab,
                         const short* __restrict__ Wt,    // 64x64 bf16, [n][k]
                         const float* __restrict__ bias,
                         float* __restrict__ T,
                         float* __restrict__ sums) {
    __shared__ float lsum[64], lssq[64];
    int tid = threadIdx.x;
    if (tid < 64) { lsum[tid] = 0.f; lssq[tid] = 0.f; }
    __syncthreads();
    int wv = tid >> 6, L = tid & 63;
    int m = L & 15, quad = L >> 4;
    int wrow = blockIdx.x * 64 + wv * 16;
    int arow = wrow + m;
    if (arow >= NN) arow = NN - 1;
    const short* Ap = (const short*)Ab;
    s16x8 a0 = *(const s16x8*)(Ap + (size_t)arow * 64 + quad * 8);
    s16x8 a1 = *(const s16x8*)(Ap + (size_t)arow * 64 + 32 + quad * 8);
    f32x4 acc[4];
    #pragma unroll
    for (int nt = 0; nt < 4; nt++) {
        int n = nt * 16 + m;
        s16x8 b0 = *(const s16x8*)(Wt + n * 64 + quad * 8);
        s16x8 b1 = *(const s16x8*)(Wt + n * 64 + 32 + quad * 8);
        acc[nt] = (f32x4){0.f, 0.f, 0.f, 0.f};
        acc[nt] = __builtin_amdgcn_mfma_f32_16x16x32_bf16(a0, b0, acc[nt], 0, 0, 0);
        acc[nt] = __builtin_amdgcn_mfma_f32_16x16x32_bf16(a1, b1, acc[nt], 0, 0, 0);
    }
    #pragma unroll
    for (int nt = 0; nt < 4; nt++) {
        int col = nt * 16 + m;
        float bv = bias[col];
        float ps = 0.f, pq = 0.f;
        #pragma unroll
        for (int r = 0; r < 4; r++) {
            int orow = wrow + quad * 4 + r;
            if (orow < NN) {
                float v = acc[nt][r] + bv;
                T[(size_t)orow * 64 + col] = v;
                ps += v;
                pq += v * v;
            }
        }
        atomicAdd(&lsum[col], ps);
        atomicAdd(&lssq[col], pq);
    }
    __syncthreads();
    if (tid < 64) {
        atomicAdd(&sums[tid], lsum[tid]);
        atomicAdd(&sums[64 + tid], lssq[tid]);
    }
}

// GEMM with A = relu(bn(T)) built on the fly -> Tout fp32 + stats
__global__ void gemm_bn_k(const float* __restrict__ Tin,
                          const float* __restrict__ stats,
                          const float* __restrict__ g, const float* __restrict__ be,
                          const short* __restrict__ Wt,    // 64x64 bf16 [n][k]
                          const float* __restrict__ bias,
                          float* __restrict__ T,
                          float* __restrict__ sums) {
    __shared__ float sc[64], sh[64], lsum[64], lssq[64];
    int tid = threadIdx.x;
    if (tid < 64) {
        float mm = stats[tid] * (1.0f / NN);
        float var = stats[64 + tid] * (1.0f / NN) - mm * mm;
        if (var < 0.f) var = 0.f;
        float s = g[tid] * rsqrtf(var + BN_EPS);
        sc[tid] = s;
        sh[tid] = be[tid] - mm * s;
        lsum[tid] = 0.f; lssq[tid] = 0.f;
    }
    __syncthreads();
    int wv = tid >> 6, L = tid & 63;
    int m = L & 15, quad = L >> 4;
    int wrow = blockIdx.x * 64 + wv * 16;
    int arow = wrow + m;
    if (arow >= NN) arow = NN - 1;
    f32x4 t0 = *(const f32x4*)(Tin + (size_t)arow * 64 + quad * 8);
    f32x4 t1 = *(const f32x4*)(Tin + (size_t)arow * 64 + quad * 8 + 4);
    f32x4 t2 = *(const f32x4*)(Tin + (size_t)arow * 64 + 32 + quad * 8);
    f32x4 t3 = *(const f32x4*)(Tin + (size_t)arow * 64 + 32 + quad * 8 + 4);
    s16x8 a0, a1;
    #pragma unroll
    for (int j = 0; j < 4; j++) {
        int k0 = quad * 8 + j, k1 = quad * 8 + 4 + j;
        float u0 = t0[j] * sc[k0] + sh[k0]; a0[j]     = f2bs(u0 > 0.f ? u0 : 0.f);
        float u1 = t1[j] * sc[k1] + sh[k1]; a0[4 + j] = f2bs(u1 > 0.f ? u1 : 0.f);
        float u2 = t2[j] * sc[32 + k0] + sh[32 + k0]; a1[j]     = f2bs(u2 > 0.f ? u2 : 0.f);
        float u3 = t3[j] * sc[32 + k1] + sh[32 + k1]; a1[4 + j] = f2bs(u3 > 0.f ? u3 : 0.f);
    }
    f32x4 acc[4];
    #pragma unroll
    for (int nt = 0; nt < 4; nt++) {
        int n = nt * 16 + m;
        s16x8 b0 = *(const s16x8*)(Wt + n * 64 + quad * 8);
        s16x8 b1 = *(const s16x8*)(Wt + n * 64 + 32 + quad * 8);
        acc[nt] = (f32x4){0.f, 0.f, 0.f, 0.f};
        acc[nt] = __builtin_amdgcn_mfma_f32_16x16x32_bf16(a0, b0, acc[nt], 0, 0, 0);
        acc[nt] = __builtin_amdgcn_mfma_f32_16x16x32_bf16(a1, b1, acc[nt], 0, 0, 0);
    }
    #pragma unroll
    for (int nt = 0; nt < 4; nt++) {
        int col = nt * 16 + m;
        float bv = bias[col];
        float ps = 0.f, pq = 0.f;
        #pragma unroll
        for (int r = 0; r < 4; r++) {
            int orow = wrow + quad * 4 + r;
            if (orow < NN) {
                float v = acc[nt][r] + bv;
                T[(size_t)orow * 64 + col] = v;
                ps += v;
                pq += v * v;
            }
        }
        atomicAdd(&lsum[col], ps);
        atomicAdd(&lssq[col], pq);
    }
    __syncthreads();
    if (tid < 64) {
        atomicAdd(&sums[tid], lsum[tid]);
        atomicAdd(&sums[64 + tid], lssq[tid]);
    }
}

// ---- BN finalize + apply + ReLU: T2 fp32 -> HCb bf16 --------------------------
__global__ void bn_k(const float* __restrict__ T, const float* __restrict__ sums,
                     const float* __restrict__ g, const float* __restrict__ be,
                     __hip_bfloat16* __restrict__ Hb) {
    __shared__ float sc[64], sh[64];
    int tid = threadIdx.x;
    if (tid < 64) {
        float m = sums[tid] * (1.0f / NN);
        float var = sums[64 + tid] * (1.0f / NN) - m * m;
        if (var < 0.f) var = 0.f;
        float s = g[tid] * rsqrtf(var + BN_EPS);
        sc[tid] = s;
        sh[tid] = be[tid] - m * s;
    }
    __syncthreads();
    int i = blockIdx.x * 256 + tid;  // over NN*16 float4s
    if (i < NN * 16) {
        int row = i >> 4, f = (i & 15) * 4;
        f32x4 v = *(const f32x4*)(T + (size_t)row * 64 + f);
        s16x4 ub;
        #pragma unroll
        for (int j = 0; j < 4; j++) {
            float w = v[j] * sc[f + j] + sh[f + j];
            ub[j] = f2bs(w > 0.f ? w : 0.f);
        }
        *(s16x4*)((short*)Hb + (size_t)row * 64 + f) = ub;
    }
}

// ---- final MFMA GEMM: [h1(bf16) | relu(bn(T2))] (Nx128) @ Wtf -> fp32 out -----
__global__ void gemm_fin_k(const __hip_bfloat16* __restrict__ H1b,
                           const float* __restrict__ T2,
                           const float* __restrict__ stats,
                           const float* __restrict__ g, const float* __restrict__ be,
                           const short* __restrict__ Wtf,   // [n][k], k=128, bf16
                           const float* __restrict__ bias,
                           float* __restrict__ O) {
    __shared__ float sc[64], sh[64];
    int tid = threadIdx.x;
    if (tid < 64) {
        float mm = stats[tid] * (1.0f / NN);
        float var = stats[64 + tid] * (1.0f / NN) - mm * mm;
        if (var < 0.f) var = 0.f;
        float s = g[tid] * rsqrtf(var + BN_EPS);
        sc[tid] = s;
        sh[tid] = be[tid] - mm * s;
    }
    __syncthreads();
    int wv = tid >> 6, L = tid & 63;
    int m = L & 15, quad = L >> 4;
    int wrow = blockIdx.x * 64 + wv * 16;
    int arow = wrow + m;
    if (arow >= NN) arow = NN - 1;
    const short* Hp = (const short*)H1b;
    s16x8 a0 = *(const s16x8*)(Hp + (size_t)arow * 64 + quad * 8);
    s16x8 a1 = *(const s16x8*)(Hp + (size_t)arow * 64 + 32 + quad * 8);
    f32x4 t0 = *(const f32x4*)(T2 + (size_t)arow * 64 + quad * 8);
    f32x4 t1 = *(const f32x4*)(T2 + (size_t)arow * 64 + quad * 8 + 4);
    f32x4 t2 = *(const f32x4*)(T2 + (size_t)arow * 64 + 32 + quad * 8);
    f32x4 t3 = *(const f32x4*)(T2 + (size_t)arow * 64 + 32 + quad * 8 + 4);
    s16x8 a2, a3;
    #pragma unroll
    for (int j = 0; j < 4; j++) {
        int k0 = quad * 8 + j, k1 = quad * 8 + 4 + j;
        float u0 = t0[j] * sc[k0] + sh[k0]; a2[j]     = f2bs(u0 > 0.f ? u0 : 0.f);
        float u1 = t1[j] * sc[k1] + sh[k1]; a2[4 + j] = f2bs(u1 > 0.f ? u1 : 0.f);
        float u2 = t2[j] * sc[32 + k0] + sh[32 + k0]; a3[j]     = f2bs(u2 > 0.f ? u2 : 0.f);
        float u3 = t3[j] * sc[32 + k1] + sh[32 + k1]; a3[4 + j] = f2bs(u3 > 0.f ? u3 : 0.f);
    }
    f32x4 acc[4];
    #pragma unroll
    for (int nt = 0; nt < 4; nt++) {
        int n = nt * 16 + m;
        s16x8 b0 = *(const s16x8*)(Wtf + n * 128 + quad * 8);
        s16x8 b1 = *(const s16x8*)(Wtf + n * 128 + 32 + quad * 8);
        s16x8 b2 = *(const s16x8*)(Wtf + n * 128 + 64 + quad * 8);
        s16x8 b3 = *(const s16x8*)(Wtf + n * 128 + 96 + quad * 8);
        acc[nt] = (f32x4){0.f, 0.f, 0.f, 0.f};
        acc[nt] = __builtin_amdgcn_mfma_f32_16x16x32_bf16(a0, b0, acc[nt], 0, 0, 0);
        acc[nt] = __builtin_amdgcn_mfma_f32_16x16x32_bf16(a1, b1, acc[nt], 0, 0, 0);
        acc[nt] = __builtin_amdgcn_mfma_f32_16x16x32_bf16(a2, b2, acc[nt], 0, 0, 0);
        acc[nt] = __builtin_amdgcn_mfma_f32_16x16x32_bf16(a3, b3, acc[nt], 0, 0, 0);
    }
    #pragma unroll
    for (int nt = 0; nt < 4; nt++) {
        int col = nt * 16 + m;
        float bv = bias[col];
        #pragma unroll
        for (int r = 0; r < 4; r++) {
            int orow = wrow + quad * 4 + r;
            if (orow < NN) O[(size_t)orow * 64 + col] = acc[nt][r] + bv;
        }
    }
}

// ---------------- launch ----------------
extern "C" void kernel_launch(void* const* d_in, const int* in_sizes, int n_in,
                              void* d_out, int out_size, void* d_ws, size_t ws_size,
                              hipStream_t stream) {
    const float* x   = (const float*)d_in[0];
    const int*   ei  = (const int*)d_in[1];
    const float* w0a = (const float*)d_in[2];
    const float* b0a = (const float*)d_in[3];
    const float* g0a = (const float*)d_in[4];
    const float* be0a= (const float*)d_in[5];
    const float* w0b = (const float*)d_in[6];
    const float* b0b = (const float*)d_in[7];
    const float* g0b = (const float*)d_in[8];
    const float* be0b= (const float*)d_in[9];
    const float* w1a = (const float*)d_in[10];
    const float* b1a = (const float*)d_in[11];
    const float* g1a = (const float*)d_in[12];
    const float* be1a= (const float*)d_in[13];
    const float* w1b = (const float*)d_in[14];
    const float* b1b = (const float*)d_in[15];
    const float* g1b = (const float*)d_in[16];
    const float* be1b= (const float*)d_in[17];
    const float* lw  = (const float*)d_in[18];
    const float* lb  = (const float*)d_in[19];
    float* out = (float*)d_out;
    (void)in_sizes; (void)n_in; (void)out_size; (void)ws_size;

    char* wsb = (char*)d_ws;
    size_t o = 0;
    auto alloc = [&](size_t bytes) -> char* {
        char* p = wsb + o;
        o += (bytes + 255) & ~(size_t)255;
        return p;
    };
    int* part = (int*)alloc(NCH * 256 * 4);
    float* sums = (float*)alloc(512 * 4);
    int* bbase = (int*)alloc(257 * 4);
    int* bres = (int*)alloc(256 * 4);
    int* off = (int*)alloc((NN + 1) * 4);
    int* adj = (int*)alloc(NE * 4);
    int* ebuf = (int*)alloc(NE * 4);
    __hip_bfloat16* Xb   = (__hip_bfloat16*)alloc((size_t)NN * 64 * 2);
    __hip_bfloat16* AGGb = (__hip_bfloat16*)alloc((size_t)NN * 64 * 2);
    __hip_bfloat16* HCb  = (__hip_bfloat16*)alloc((size_t)NN * 64 * 2);
    float* T  = (float*)alloc((size_t)NN * 64 * 4);
    float* T2 = (float*)alloc((size_t)NN * 64 * 4);
    short* Wt0a = (short*)alloc(4096 * 2);
    short* Wt0b = (short*)alloc(4096 * 2);
    short* Wt1a = (short*)alloc(4096 * 2);
    short* Wt1b = (short*)alloc(4096 * 2);
    short* Wtf  = (short*)alloc(8192 * 2);

    const int* src = ei;
    const int* dst = ei + NE;

    prep_k<<<3326, 256, 0, stream>>>(dst, part, x, Xb, w0a, w0b, w1a, w1b, lw,
                                     Wt0a, Wt0b, Wt1a, Wt1b, Wtf);
    bscan_k<<<1, 256, 0, stream>>>(part, bbase, bres, off, sums);
    bscatter_k<<<NCH, 256, 0, stream>>>(src, dst, bres, ebuf);
    csr_k<<<NBK, 256, 0, stream>>>(bbase, ebuf, off, adj);

    const int ggrid = NN / 4;                  // 12500
    const int mgrid = (NN + 63) / 64;          // 782
    const int agrid = (NN * 16 + 255) / 256;   // 3125

    // ---- layer 0 ----
    gather_k<<<ggrid, 256, 0, stream>>>(Xb, off, adj, AGGb);
    gemm_a_k<<<mgrid, 256, 0, stream>>>(AGGb, Wt0a, b0a, T, sums + 0);
    gemm_bn_k<<<mgrid, 256, 0, stream>>>(T, sums + 0, g0a, be0a, Wt0b, b0b, T2, sums + 128);
    bn_k<<<agrid, 256, 0, stream>>>(T2, sums + 128, g0b, be0b, HCb);          // h1 bf16

    // ---- layer 1 ----
    gather_k<<<ggrid, 256, 0, stream>>>(HCb, off, adj, AGGb);
    gemm_a_k<<<mgrid, 256, 0, stream>>>(AGGb, Wt1a, b1a, T, sums + 256);
    gemm_bn_k<<<mgrid, 256, 0, stream>>>(T, sums + 256, g1a, be1a, Wt1b, b1b, T2, sums + 384);

    // ---- JK cat + final linear (h2 BN fused; h1 read as bf16) ----
    gemm_fin_k<<<mgrid, 256, 0, stream>>>(HCb, T2, sums + 384, g1b, be1b, Wtf, lb, out);
}